// Round 1
// baseline (1264.762 us; speedup 1.0000x reference)
//
#include <hip/hip_runtime.h>

// Problem constants
#define NB    2
#define NCH   256
#define HH    40
#define WW    40
#define HWT   1600     // H*W
#define HBs   80
#define WBs   80
#define HWB   6400     // HB*WB
#define NHD   8
#define BN    16       // B*NH

// Workspace layout (floats):
//  Ptop: [3][16][1600][32]  = 2,457,600   (kqv, b*NH+head, pos, d)  position-major
//  Pbot: [3][16][6400][32]  = 9,830,400
//  TR  : [2][1600][256]     =   819,200   (b, pos, head*32+v)       position-major
//  BA  : [2][6400][256]     = 3,276,800   (b, pos, head*32+d)       zeroed, atomicAdd target
#define OFF_PTOP 0
#define OFF_PBOT 2457600
#define OFF_TR   12288000
#define OFF_BA   13107200
// total = 16,384,000 floats = 65,536,000 bytes

// ---------------------------------------------------------------------------
// Projection GEMM: P[kqv][bh][pos][32] = W[kqv] (256x256) @ X[b] (256 x npos)
// Tile 64 oc x 64 pos, 256 threads, 4x4 micro-tile. K = 256 in chunks of 16.
// ---------------------------------------------------------------------------
__global__ __launch_bounds__(256) void proj_gemm(
    const float* __restrict__ X,
    const float* __restrict__ Wk,
    const float* __restrict__ Wq,
    const float* __restrict__ Wv,
    float* __restrict__ P,
    int npos)
{
  __shared__ float As[16][64];   // [k][oc]
  __shared__ float Bs[16][64];   // [k][pos]
  const int tid  = threadIdx.x;
  const int b    = blockIdx.z;
  const int oc0  = blockIdx.y * 64;   // 0..704 (768 oc total = 3 kqv * 256)
  const int pos0 = blockIdx.x * 64;
  const int tx   = tid & 15;          // -> oc quad (store-coalescing along d)
  const int ty   = tid >> 4;          // -> pos quad
  const int kqv  = oc0 >> 8;
  const int ocr  = oc0 & 255;
  const float* Wsel = (kqv == 0) ? Wk : ((kqv == 1) ? Wq : Wv);
  const float* Xb   = X + (size_t)b * NCH * npos;

  const int la_r = tid >> 2;          // 0..63 oc-in-tile
  const int la_c = (tid & 3) * 4;     // k
  const int lb_r = tid >> 4;          // 0..15 k
  const int lb_c = (tid & 15) * 4;    // pos

  float acc[4][4];
#pragma unroll
  for (int i = 0; i < 4; ++i)
#pragma unroll
    for (int j = 0; j < 4; ++j) acc[i][j] = 0.f;

  for (int kt = 0; kt < 256; kt += 16) {
    float4 av = *(const float4*)&Wsel[(size_t)(ocr + la_r) * 256 + kt + la_c];
    float4 bv = *(const float4*)&Xb[(size_t)(kt + lb_r) * npos + pos0 + lb_c];
    __syncthreads();
    As[la_c + 0][la_r] = av.x;
    As[la_c + 1][la_r] = av.y;
    As[la_c + 2][la_r] = av.z;
    As[la_c + 3][la_r] = av.w;
    *(float4*)&Bs[lb_r][lb_c] = bv;
    __syncthreads();
#pragma unroll
    for (int kk = 0; kk < 16; ++kk) {
      float a[4], bb[4];
      *(float4*)a  = *(const float4*)&As[kk][tx * 4];
      *(float4*)bb = *(const float4*)&Bs[kk][ty * 4];
#pragma unroll
      for (int i = 0; i < 4; ++i)
#pragma unroll
        for (int j = 0; j < 4; ++j) acc[i][j] += a[i] * bb[j];
    }
  }

  // store: oc = oc0 + tx*4 + i  ->  (kqv, head, d). 4 consecutive d => float4
  const int ocl  = oc0 + tx * 4;
  const int hd   = ocl & 255;
  const int head = hd >> 5;
  const int d0   = hd & 31;
  const int bh   = b * NHD + head;
  float* Pb = P + (size_t)(kqv * BN + bh) * npos * 32;
#pragma unroll
  for (int j = 0; j < 4; ++j) {
    const int pos = pos0 + ty * 4 + j;
    *(float4*)&Pb[(size_t)pos * 32 + d0] =
        make_float4(acc[0][j], acc[1][j], acc[2][j], acc[3][j]);
  }
}

// ---------------------------------------------------------------------------
// Attention. One wave handles 2 positions n; lane = (n_sub = lane/32, v = lane%32).
// Rows (reference semantics, incl. the reshape scramble):
//   row 0       = top proj (clean d = 0..31)
//   row 1+a, b  = bot flat index a*32+b of the d-major vector F[d*25+p]
// Staged into LDS row-major [26][32] (linear = 32 + d*25 + p for bot entries).
// M-form: M[x][v] = sum_j Q[j][x] * V[j][v]  (M column per lane, 32 regs)
//         out[i][v] = sum_x K[i][x] * M[x][v]
// Output scramble on rows i>=1: flat=(i-1)*32+v -> d=flat/25, p=flat%25;
// atomicAdd into BA at (pos(p), head*32+d)  [fold with pad-drop].
// ---------------------------------------------------------------------------
__device__ __forceinline__ void stage_rows(
    float* dst,                        // 832-float slot
    const float* __restrict__ Ptopr,   // top row (32 floats) for this (kqv,bh,hw)
    const float* __restrict__ Pbotp,   // bot plane base for this (kqv,bh)
    int ho, int wo, int v, float scl)
{
  dst[v] = Ptopr[v] * scl;
#pragma unroll
  for (int p = 0; p < 25; ++p) {
    const int ki = p / 5, kj = p % 5;
    const int hb = 2 * ho - 2 + ki;
    const int wb = 2 * wo - 2 + kj;
    float val = 0.f;
    if (hb >= 0 && hb < HBs && wb >= 0 && wb < WBs)
      val = Pbotp[(size_t)(hb * WBs + wb) * 32 + v] * scl;
    dst[32 + v * 25 + p] = val;   // scrambled write: flat = d*25+p (d == v here)
  }
}

__global__ __launch_bounds__(256) void attn_kernel(
    const float* __restrict__ Ptop,
    const float* __restrict__ Pbot,
    float* __restrict__ TR,
    float* __restrict__ BA)
{
  __shared__ float SQ[8][832];   // Q rows (scaled); reused for K in phase B
  __shared__ float SV[8][832];

  const int tid  = threadIdx.x;
  const int widx = tid >> 6;
  const int lane = tid & 63;
  const int nsub = lane >> 5;
  const int v    = lane & 31;
  const int slot = widx * 2 + nsub;
  const int n    = (blockIdx.x * 4 + widx) * 2 + nsub;
  const int b    = n / (NHD * HWT);
  const int head = (n / HWT) % NHD;
  const int hw   = n % HWT;
  const int ho   = hw / WW, wo = hw % WW;
  const int bh   = b * NHD + head;
  const float scale = 0.17677669529663687f;  // 1/sqrt(32)

  float* SQs = &SQ[slot][0];
  float* SVs = &SV[slot][0];

  // stage Q (pre-scaled) and V
  stage_rows(SQs, Ptop + ((size_t)(1 * BN + bh) * HWT + hw) * 32,
             Pbot + (size_t)(1 * BN + bh) * HWB * 32, ho, wo, v, scale);
  stage_rows(SVs, Ptop + ((size_t)(2 * BN + bh) * HWT + hw) * 32,
             Pbot + (size_t)(2 * BN + bh) * HWB * 32, ho, wo, v, 1.f);

  // phase A: M[x][v] = sum_j Q[j][x] * V[j][v]
  float m[32];
#pragma unroll
  for (int x = 0; x < 32; ++x) m[x] = 0.f;

  for (int j = 0; j < 26; ++j) {
    const float vv = SVs[j * 32 + v];
    float q[32];
#pragma unroll
    for (int c = 0; c < 8; ++c) {
      float4 t = *(const float4*)&SQs[j * 32 + c * 4];
      q[c * 4 + 0] = t.x; q[c * 4 + 1] = t.y;
      q[c * 4 + 2] = t.z; q[c * 4 + 3] = t.w;
    }
#pragma unroll
    for (int x = 0; x < 32; ++x) m[x] += q[x] * vv;
  }

  // restage K into SQ slot (unscaled); same-lane-group private -> no barrier
  stage_rows(SQs, Ptop + ((size_t)(0 * BN + bh) * HWT + hw) * 32,
             Pbot + (size_t)(0 * BN + bh) * HWB * 32, ho, wo, v, 1.f);

  // phase B: out[i][v] = sum_x K[i][x] * m[x]
  // i = 0 (top return)
  {
    float k_[32];
#pragma unroll
    for (int c = 0; c < 8; ++c) {
      float4 t = *(const float4*)&SQs[c * 4];
      k_[c * 4 + 0] = t.x; k_[c * 4 + 1] = t.y;
      k_[c * 4 + 2] = t.z; k_[c * 4 + 3] = t.w;
    }
    float s0 = 0.f, s1 = 0.f, s2 = 0.f, s3 = 0.f;
#pragma unroll
    for (int x = 0; x < 8; ++x) {
      s0 += k_[x * 4 + 0] * m[x * 4 + 0];
      s1 += k_[x * 4 + 1] * m[x * 4 + 1];
      s2 += k_[x * 4 + 2] * m[x * 4 + 2];
      s3 += k_[x * 4 + 3] * m[x * 4 + 3];
    }
    TR[((size_t)(b * HWT + hw)) * 256 + head * 32 + v] = (s0 + s1) + (s2 + s3);
  }
  // i = 1..25 (bot rows, output scramble + fold via atomics)
  for (int i = 1; i < 26; ++i) {
    float k_[32];
#pragma unroll
    for (int c = 0; c < 8; ++c) {
      float4 t = *(const float4*)&SQs[i * 32 + c * 4];
      k_[c * 4 + 0] = t.x; k_[c * 4 + 1] = t.y;
      k_[c * 4 + 2] = t.z; k_[c * 4 + 3] = t.w;
    }
    float s0 = 0.f, s1 = 0.f, s2 = 0.f, s3 = 0.f;
#pragma unroll
    for (int x = 0; x < 8; ++x) {
      s0 += k_[x * 4 + 0] * m[x * 4 + 0];
      s1 += k_[x * 4 + 1] * m[x * 4 + 1];
      s2 += k_[x * 4 + 2] * m[x * 4 + 2];
      s3 += k_[x * 4 + 3] * m[x * 4 + 3];
    }
    const float o = (s0 + s1) + (s2 + s3);
    const int flat = (i - 1) * 32 + v;
    const int d  = flat / 25;
    const int p  = flat % 25;
    const int ki = p / 5, kj = p % 5;
    const int hb = 2 * ho - 2 + ki;
    const int wb = 2 * wo - 2 + kj;
    if (hb >= 0 && hb < HBs && wb >= 0 && wb < WBs)
      atomicAdd(&BA[((size_t)(b * HWB + hb * WBs + wb)) * 256 + head * 32 + d], o);
  }
}

// ---------------------------------------------------------------------------
// Fuse GEMM: Out[b][co][pos] = Wf (256x256) @ Xp[b][pos][256]^T   (pos-major X)
// ---------------------------------------------------------------------------
__global__ __launch_bounds__(256) void fuse_gemm(
    const float* __restrict__ Xp,   // [B][npos][256]
    const float* __restrict__ Wf,   // [256][256]
    float* __restrict__ Out,        // [B][256][npos]
    int npos)
{
  __shared__ float As[16][64];   // [k][co]
  __shared__ float Bs[16][64];   // [k][pos]
  const int tid  = threadIdx.x;
  const int b    = blockIdx.z;
  const int co0  = blockIdx.y * 64;
  const int pos0 = blockIdx.x * 64;
  const int tx   = tid & 15;      // -> pos quad (store coalescing along pos)
  const int ty   = tid >> 4;      // -> co quad
  const float* Xb = Xp + (size_t)b * npos * 256;

  const int la_r = tid >> 2;      // 0..63
  const int la_c = (tid & 3) * 4; // k

  float acc[4][4];
#pragma unroll
  for (int i = 0; i < 4; ++i)
#pragma unroll
    for (int j = 0; j < 4; ++j) acc[i][j] = 0.f;

  for (int kt = 0; kt < 256; kt += 16) {
    float4 av = *(const float4*)&Wf[(size_t)(co0 + la_r) * 256 + kt + la_c];
    float4 bv = *(const float4*)&Xb[(size_t)(pos0 + la_r) * 256 + kt + la_c];
    __syncthreads();
    As[la_c + 0][la_r] = av.x;
    As[la_c + 1][la_r] = av.y;
    As[la_c + 2][la_r] = av.z;
    As[la_c + 3][la_r] = av.w;
    Bs[la_c + 0][la_r] = bv.x;
    Bs[la_c + 1][la_r] = bv.y;
    Bs[la_c + 2][la_r] = bv.z;
    Bs[la_c + 3][la_r] = bv.w;
    __syncthreads();
#pragma unroll
    for (int kk = 0; kk < 16; ++kk) {
      float a[4], bb[4];
      *(float4*)a  = *(const float4*)&As[kk][ty * 4];
      *(float4*)bb = *(const float4*)&Bs[kk][tx * 4];
#pragma unroll
      for (int i = 0; i < 4; ++i)
#pragma unroll
        for (int j = 0; j < 4; ++j) acc[i][j] += a[i] * bb[j];
    }
  }

  float* Ob = Out + (size_t)b * NCH * npos;
#pragma unroll
  for (int i = 0; i < 4; ++i) {
    const int co = co0 + ty * 4 + i;
    *(float4*)&Ob[(size_t)co * npos + pos0 + tx * 4] =
        make_float4(acc[i][0], acc[i][1], acc[i][2], acc[i][3]);
  }
}

// ---------------------------------------------------------------------------
extern "C" void kernel_launch(void* const* d_in, const int* in_sizes, int n_in,
                              void* d_out, int out_size, void* d_ws, size_t ws_size,
                              hipStream_t stream) {
  (void)in_sizes; (void)n_in; (void)out_size; (void)ws_size;
  const float* top = (const float*)d_in[0];
  const float* bot = (const float*)d_in[1];
  const float* wtk = (const float*)d_in[2];
  const float* wtq = (const float*)d_in[3];
  const float* wtv = (const float*)d_in[4];
  const float* wbk = (const float*)d_in[5];
  const float* wbq = (const float*)d_in[6];
  const float* wbv = (const float*)d_in[7];
  const float* wtf = (const float*)d_in[8];
  const float* wbf = (const float*)d_in[9];

  float* ws   = (float*)d_ws;
  float* Ptop = ws + OFF_PTOP;
  float* Pbot = ws + OFF_PBOT;
  float* TR   = ws + OFF_TR;
  float* BA   = ws + OFF_BA;

  // zero the fold accumulator (ws is poisoned 0xAA before every launch)
  hipMemsetAsync(BA, 0, (size_t)NB * HWB * 256 * sizeof(float), stream);

  proj_gemm<<<dim3(HWT / 64, 12, NB), 256, 0, stream>>>(top, wtk, wtq, wtv, Ptop, HWT);
  proj_gemm<<<dim3(HWB / 64, 12, NB), 256, 0, stream>>>(bot, wbk, wbq, wbv, Pbot, HWB);
  attn_kernel<<<dim3(25600 / 8), 256, 0, stream>>>(Ptop, Pbot, TR, BA);
  fuse_gemm<<<dim3(HWT / 64, 4, NB), 256, 0, stream>>>(TR, wtf, (float*)d_out, HWT);
  fuse_gemm<<<dim3(HWB / 64, 4, NB), 256, 0, stream>>>(BA, wbf, (float*)d_out + (size_t)NB * NCH * HWT, HWB);
}

// Round 2
// 534.537 us; speedup vs baseline: 2.3661x; 2.3661x over previous
//
#include <hip/hip_runtime.h>

// Problem constants
#define NB    2
#define NCH   256
#define HH    40
#define WW    40
#define HWT   1600     // H*W
#define HBs   80
#define WBs   80
#define HWB   6400     // HB*WB
#define NHD   8
#define BN    16       // B*NH

// Workspace layout (floats):
//  Ptop  : [3][16][1600][32]  =  2,457,600   (kqv, b*NH+head, pos, d)
//  Pbot  : [3][16][6400][32]  =  9,830,400
//  TR    : [2][1600][256]     =    819,200   (b, pos, head*32+v)
//  BA    : [2][6400][256]     =  3,276,800   (b, pos, head*32+d)
//  AttOut: [16][1600][800]    = 20,480,000   (bh, hw, flat = d*25+p)  [dense path]
#define OFF_PTOP 0
#define OFF_PBOT 2457600
#define OFF_TR   12288000
#define OFF_BA   13107200
#define OFF_ATT  16384000
#define WS_NEED_DENSE  (36864000ULL * 4ULL)   // 147.5 MB
// fallback (atomic) path needs only 65.5 MB

// ---------------------------------------------------------------------------
// Projection GEMM: P[kqv][bh][pos][32] = W[kqv] (256x256) @ X[b] (256 x npos)
// ---------------------------------------------------------------------------
__global__ __launch_bounds__(256) void proj_gemm(
    const float* __restrict__ X,
    const float* __restrict__ Wk,
    const float* __restrict__ Wq,
    const float* __restrict__ Wv,
    float* __restrict__ P,
    int npos)
{
  __shared__ float As[16][64];   // [k][oc]
  __shared__ float Bs[16][64];   // [k][pos]
  const int tid  = threadIdx.x;
  const int b    = blockIdx.z;
  const int oc0  = blockIdx.y * 64;   // 0..704 (768 oc total = 3 kqv * 256)
  const int pos0 = blockIdx.x * 64;
  const int tx   = tid & 15;          // -> oc quad (store-coalescing along d)
  const int ty   = tid >> 4;          // -> pos quad
  const int kqv  = oc0 >> 8;
  const int ocr  = oc0 & 255;
  const float* Wsel = (kqv == 0) ? Wk : ((kqv == 1) ? Wq : Wv);
  const float* Xb   = X + (size_t)b * NCH * npos;

  const int la_r = tid >> 2;          // 0..63 oc-in-tile
  const int la_c = (tid & 3) * 4;     // k
  const int lb_r = tid >> 4;          // 0..15 k
  const int lb_c = (tid & 15) * 4;    // pos

  float acc[4][4];
#pragma unroll
  for (int i = 0; i < 4; ++i)
#pragma unroll
    for (int j = 0; j < 4; ++j) acc[i][j] = 0.f;

  for (int kt = 0; kt < 256; kt += 16) {
    float4 av = *(const float4*)&Wsel[(size_t)(ocr + la_r) * 256 + kt + la_c];
    float4 bv = *(const float4*)&Xb[(size_t)(kt + lb_r) * npos + pos0 + lb_c];
    __syncthreads();
    As[la_c + 0][la_r] = av.x;
    As[la_c + 1][la_r] = av.y;
    As[la_c + 2][la_r] = av.z;
    As[la_c + 3][la_r] = av.w;
    *(float4*)&Bs[lb_r][lb_c] = bv;
    __syncthreads();
#pragma unroll
    for (int kk = 0; kk < 16; ++kk) {
      float a[4], bb[4];
      *(float4*)a  = *(const float4*)&As[kk][tx * 4];
      *(float4*)bb = *(const float4*)&Bs[kk][ty * 4];
#pragma unroll
      for (int i = 0; i < 4; ++i)
#pragma unroll
        for (int j = 0; j < 4; ++j) acc[i][j] += a[i] * bb[j];
    }
  }

  const int ocl  = oc0 + tx * 4;
  const int hd   = ocl & 255;
  const int head = hd >> 5;
  const int d0   = hd & 31;
  const int bh   = b * NHD + head;
  float* Pb = P + (size_t)(kqv * BN + bh) * npos * 32;
#pragma unroll
  for (int j = 0; j < 4; ++j) {
    const int pos = pos0 + ty * 4 + j;
    *(float4*)&Pb[(size_t)pos * 32 + d0] =
        make_float4(acc[0][j], acc[1][j], acc[2][j], acc[3][j]);
  }
}

// ---------------------------------------------------------------------------
// Staging helper: build one 26x32 row-major matrix in a LDS slot.
//   row 0      = top proj (clean d = 0..31)
//   row 1+a, b = bot flat index a*32+b of the d-major vector F[d*25+p]
// LDS linear layout offset(row j, col x) = j*32+x  == 32 + d*25 + p for bot.
// Scrambled write (lane v == d, stride 25): banks (25v+p)%32, conflict-free.
// ---------------------------------------------------------------------------
__device__ __forceinline__ void stage_rows(
    float* dst,                        // 832-float slot
    const float* __restrict__ Ptopr,   // top row (32 floats)
    const float* __restrict__ Pbotp,   // bot plane base for this (kqv,bh)
    int ho, int wo, int v, float scl)
{
  dst[v] = Ptopr[v] * scl;
#pragma unroll
  for (int p = 0; p < 25; ++p) {
    const int ki = p / 5, kj = p % 5;
    const int hb = 2 * ho - 2 + ki;
    const int wb = 2 * wo - 2 + kj;
    float val = 0.f;
    if (hb >= 0 && hb < HBs && wb >= 0 && wb < WBs)
      val = Pbotp[(size_t)(hb * WBs + wb) * 32 + v] * scl;
    dst[32 + v * 25 + p] = val;
  }
}

// ---------------------------------------------------------------------------
// Attention v2 (dense path, no atomics). One half-wave per position n.
// M[x][v] = sum_j Q[j][x]*V[j][v] (scaled);  out[i][v] = sum_x K[i][x]*M[x][v].
// Bot rows stored densely: AttOut[n][ (i-1)*32+v ]  (== d*25+p index).
// ---------------------------------------------------------------------------
__global__ __launch_bounds__(256, 3) void attn_dense(
    const float* __restrict__ Ptop,
    const float* __restrict__ Pbot,
    float* __restrict__ TR,
    float* __restrict__ AttOut)
{
  __shared__ float SQ[8][832];   // Q (scaled), reused for K in phase B
  __shared__ float SV[8][832];

  const int tid  = threadIdx.x;
  const int widx = tid >> 6;
  const int lane = tid & 63;
  const int nsub = lane >> 5;
  const int v    = lane & 31;
  const int slot = widx * 2 + nsub;
  const int n    = (blockIdx.x * 4 + widx) * 2 + nsub;
  const int b    = n / (NHD * HWT);
  const int head = (n / HWT) % NHD;
  const int hw   = n % HWT;
  const int ho   = hw / WW, wo = hw % WW;
  const int bh   = b * NHD + head;
  const float scale = 0.17677669529663687f;  // 1/sqrt(32)

  float* SQs = &SQ[slot][0];
  float* SVs = &SV[slot][0];

  stage_rows(SQs, Ptop + ((size_t)(1 * BN + bh) * HWT + hw) * 32,
             Pbot + (size_t)(1 * BN + bh) * HWB * 32, ho, wo, v, scale);
  stage_rows(SVs, Ptop + ((size_t)(2 * BN + bh) * HWT + hw) * 32,
             Pbot + (size_t)(2 * BN + bh) * HWB * 32, ho, wo, v, 1.f);

  // phase A: M column v in registers
  float m[32];
#pragma unroll
  for (int x = 0; x < 32; ++x) m[x] = 0.f;

#pragma unroll 2
  for (int j = 0; j < 26; ++j) {
    const float vv = SVs[j * 32 + v];
    const float* qr = &SQs[j * 32];
#pragma unroll
    for (int c = 0; c < 8; ++c) {
      float4 t = *(const float4*)&qr[c * 4];
      m[c * 4 + 0] += t.x * vv;
      m[c * 4 + 1] += t.y * vv;
      m[c * 4 + 2] += t.z * vv;
      m[c * 4 + 3] += t.w * vv;
    }
  }

  // restage K into the Q slot (same-half-wave private; DS ops in-order)
  stage_rows(SQs, Ptop + ((size_t)(0 * BN + bh) * HWT + hw) * 32,
             Pbot + (size_t)(0 * BN + bh) * HWB * 32, ho, wo, v, 1.f);

  // phase B
  float* AOn = AttOut + (size_t)n * 800;
  float* TRn = TR + ((size_t)(b * HWT + hw)) * 256 + head * 32;
#pragma unroll 2
  for (int i = 0; i < 26; ++i) {
    const float* kr = &SQs[i * 32];
    float s0 = 0.f, s1 = 0.f, s2 = 0.f, s3 = 0.f;
#pragma unroll
    for (int c = 0; c < 8; ++c) {
      float4 t = *(const float4*)&kr[c * 4];
      s0 += t.x * m[c * 4 + 0];
      s1 += t.y * m[c * 4 + 1];
      s2 += t.z * m[c * 4 + 2];
      s3 += t.w * m[c * 4 + 3];
    }
    const float o = (s0 + s1) + (s2 + s3);
    if (i == 0) TRn[v] = o;
    else        AOn[(i - 1) * 32 + v] = o;
  }
}

// ---------------------------------------------------------------------------
// Fold gather: BA[b][hb*80+wb][head*32+d] = sum over <=9 windows of
//   AttOut[(b*8+head)][ho*40+wo][d*25+p],  ki=hb+2-2ho, kj=wb+2-2wo.
// Thread t: d fastest (coalesced BA write), then head, then pixel, then b.
// ---------------------------------------------------------------------------
__global__ __launch_bounds__(256) void fold_gather(
    const float* __restrict__ AttOut,
    float* __restrict__ BA)
{
  const int t    = blockIdx.x * 256 + threadIdx.x;
  const int d    = t & 31;
  const int head = (t >> 5) & 7;
  const int pix  = (t >> 8) % HWB;
  const int b    = (t >> 8) / HWB;
  const int hb   = pix / WBs, wb = pix % WBs;

  const float* A = AttOut + (size_t)(b * NHD + head) * HWT * 800;
  float s = 0.f;
  for (int ki = (hb & 1); ki < 5; ki += 2) {
    const int ho = (hb + 2 - ki) >> 1;
    if (ho < 0 || ho >= HH) continue;
    for (int kj = (wb & 1); kj < 5; kj += 2) {
      const int wo = (wb + 2 - kj) >> 1;
      if (wo < 0 || wo >= WW) continue;
      s += A[(size_t)(ho * WW + wo) * 800 + d * 25 + ki * 5 + kj];
    }
  }
  BA[(size_t)(b * HWB + pix) * 256 + head * 32 + d] = s;
}

// ---------------------------------------------------------------------------
// Fallback attention (atomic fold) — used only if ws_size is too small.
// ---------------------------------------------------------------------------
__global__ __launch_bounds__(256) void attn_atomic(
    const float* __restrict__ Ptop,
    const float* __restrict__ Pbot,
    float* __restrict__ TR,
    float* __restrict__ BA)
{
  __shared__ float SQ[8][832];
  __shared__ float SV[8][832];

  const int tid  = threadIdx.x;
  const int widx = tid >> 6;
  const int lane = tid & 63;
  const int nsub = lane >> 5;
  const int v    = lane & 31;
  const int slot = widx * 2 + nsub;
  const int n    = (blockIdx.x * 4 + widx) * 2 + nsub;
  const int b    = n / (NHD * HWT);
  const int head = (n / HWT) % NHD;
  const int hw   = n % HWT;
  const int ho   = hw / WW, wo = hw % WW;
  const int bh   = b * NHD + head;
  const float scale = 0.17677669529663687f;

  float* SQs = &SQ[slot][0];
  float* SVs = &SV[slot][0];

  stage_rows(SQs, Ptop + ((size_t)(1 * BN + bh) * HWT + hw) * 32,
             Pbot + (size_t)(1 * BN + bh) * HWB * 32, ho, wo, v, scale);
  stage_rows(SVs, Ptop + ((size_t)(2 * BN + bh) * HWT + hw) * 32,
             Pbot + (size_t)(2 * BN + bh) * HWB * 32, ho, wo, v, 1.f);

  float m[32];
#pragma unroll
  for (int x = 0; x < 32; ++x) m[x] = 0.f;

#pragma unroll 2
  for (int j = 0; j < 26; ++j) {
    const float vv = SVs[j * 32 + v];
    const float* qr = &SQs[j * 32];
#pragma unroll
    for (int c = 0; c < 8; ++c) {
      float4 t = *(const float4*)&qr[c * 4];
      m[c * 4 + 0] += t.x * vv;
      m[c * 4 + 1] += t.y * vv;
      m[c * 4 + 2] += t.z * vv;
      m[c * 4 + 3] += t.w * vv;
    }
  }

  stage_rows(SQs, Ptop + ((size_t)(0 * BN + bh) * HWT + hw) * 32,
             Pbot + (size_t)(0 * BN + bh) * HWB * 32, ho, wo, v, 1.f);

  for (int i = 0; i < 26; ++i) {
    const float* kr = &SQs[i * 32];
    float s0 = 0.f, s1 = 0.f, s2 = 0.f, s3 = 0.f;
#pragma unroll
    for (int c = 0; c < 8; ++c) {
      float4 t = *(const float4*)&kr[c * 4];
      s0 += t.x * m[c * 4 + 0];
      s1 += t.y * m[c * 4 + 1];
      s2 += t.z * m[c * 4 + 2];
      s3 += t.w * m[c * 4 + 3];
    }
    const float o = (s0 + s1) + (s2 + s3);
    if (i == 0) {
      TR[((size_t)(b * HWT + hw)) * 256 + head * 32 + v] = o;
    } else {
      const int flat = (i - 1) * 32 + v;
      const int dd = flat / 25;
      const int p  = flat % 25;
      const int ki = p / 5, kj = p % 5;
      const int hb = 2 * ho - 2 + ki;
      const int wb = 2 * wo - 2 + kj;
      if (hb >= 0 && hb < HBs && wb >= 0 && wb < WBs)
        atomicAdd(&BA[((size_t)(b * HWB + hb * WBs + wb)) * 256 + head * 32 + dd], o);
    }
  }
}

// ---------------------------------------------------------------------------
// Fuse GEMM: Out[b][co][pos] = Wf (256x256) @ Xp[b][pos][256]^T
// ---------------------------------------------------------------------------
__global__ __launch_bounds__(256) void fuse_gemm(
    const float* __restrict__ Xp,   // [B][npos][256]
    const float* __restrict__ Wf,   // [256][256]
    float* __restrict__ Out,        // [B][256][npos]
    int npos)
{
  __shared__ float As[16][64];
  __shared__ float Bs[16][64];
  const int tid  = threadIdx.x;
  const int b    = blockIdx.z;
  const int co0  = blockIdx.y * 64;
  const int pos0 = blockIdx.x * 64;
  const int tx   = tid & 15;
  const int ty   = tid >> 4;
  const float* Xb = Xp + (size_t)b * npos * 256;

  const int la_r = tid >> 2;
  const int la_c = (tid & 3) * 4;

  float acc[4][4];
#pragma unroll
  for (int i = 0; i < 4; ++i)
#pragma unroll
    for (int j = 0; j < 4; ++j) acc[i][j] = 0.f;

  for (int kt = 0; kt < 256; kt += 16) {
    float4 av = *(const float4*)&Wf[(size_t)(co0 + la_r) * 256 + kt + la_c];
    float4 bv = *(const float4*)&Xb[(size_t)(pos0 + la_r) * 256 + kt + la_c];
    __syncthreads();
    As[la_c + 0][la_r] = av.x;
    As[la_c + 1][la_r] = av.y;
    As[la_c + 2][la_r] = av.z;
    As[la_c + 3][la_r] = av.w;
    Bs[la_c + 0][la_r] = bv.x;
    Bs[la_c + 1][la_r] = bv.y;
    Bs[la_c + 2][la_r] = bv.z;
    Bs[la_c + 3][la_r] = bv.w;
    __syncthreads();
#pragma unroll
    for (int kk = 0; kk < 16; ++kk) {
      float a[4], bb[4];
      *(float4*)a  = *(const float4*)&As[kk][ty * 4];
      *(float4*)bb = *(const float4*)&Bs[kk][tx * 4];
#pragma unroll
      for (int i = 0; i < 4; ++i)
#pragma unroll
        for (int j = 0; j < 4; ++j) acc[i][j] += a[i] * bb[j];
    }
  }

  float* Ob = Out + (size_t)b * NCH * npos;
#pragma unroll
  for (int i = 0; i < 4; ++i) {
    const int co = co0 + ty * 4 + i;
    *(float4*)&Ob[(size_t)co * npos + pos0 + tx * 4] =
        make_float4(acc[i][0], acc[i][1], acc[i][2], acc[i][3]);
  }
}

// ---------------------------------------------------------------------------
extern "C" void kernel_launch(void* const* d_in, const int* in_sizes, int n_in,
                              void* d_out, int out_size, void* d_ws, size_t ws_size,
                              hipStream_t stream) {
  (void)in_sizes; (void)n_in; (void)out_size;
  const float* top = (const float*)d_in[0];
  const float* bot = (const float*)d_in[1];
  const float* wtk = (const float*)d_in[2];
  const float* wtq = (const float*)d_in[3];
  const float* wtv = (const float*)d_in[4];
  const float* wbk = (const float*)d_in[5];
  const float* wbq = (const float*)d_in[6];
  const float* wbv = (const float*)d_in[7];
  const float* wtf = (const float*)d_in[8];
  const float* wbf = (const float*)d_in[9];

  float* ws   = (float*)d_ws;
  float* Ptop = ws + OFF_PTOP;
  float* Pbot = ws + OFF_PBOT;
  float* TR   = ws + OFF_TR;
  float* BA   = ws + OFF_BA;
  float* Att  = ws + OFF_ATT;

  proj_gemm<<<dim3(HWT / 64, 12, NB), 256, 0, stream>>>(top, wtk, wtq, wtv, Ptop, HWT);
  proj_gemm<<<dim3(HWB / 64, 12, NB), 256, 0, stream>>>(bot, wbk, wbq, wbv, Pbot, HWB);

  if (ws_size >= WS_NEED_DENSE) {
    // dense path: no atomics; fold via gather (BA fully overwritten, no memset)
    attn_dense<<<dim3(25600 / 8), 256, 0, stream>>>(Ptop, Pbot, TR, Att);
    fold_gather<<<dim3((NB * NHD * HWB * 32) / 256), 256, 0, stream>>>(Att, BA);
  } else {
    hipMemsetAsync(BA, 0, (size_t)NB * HWB * 256 * sizeof(float), stream);
    attn_atomic<<<dim3(25600 / 8), 256, 0, stream>>>(Ptop, Pbot, TR, BA);
  }

  fuse_gemm<<<dim3(HWT / 64, 4, NB), 256, 0, stream>>>(TR, wtf, (float*)d_out, HWT);
  fuse_gemm<<<dim3(HWB / 64, 4, NB), 256, 0, stream>>>(BA, wbf, (float*)d_out + (size_t)NB * NCH * HWT, HWB);
}

// Round 4
// 366.066 us; speedup vs baseline: 3.4550x; 1.4602x over previous
//
#include <hip/hip_runtime.h>

// Problem constants
#define NB    2
#define NCH   256
#define HH    40
#define WW    40
#define HWT   1600     // H*W
#define HBs   80
#define WBs   80
#define HWB   6400     // HB*WB
#define NHD   8
#define BN    16       // B*NH

// Workspace layout (floats):
//  Ptop  : [3][16][1600][32]  =  2,457,600   (kqv, b*NH+head, pos, d)
//  Pbot  : [3][16][6400][32]  =  9,830,400
//  TR    : [2][1600][256]     =    819,200   (b, pos, head*32+v)
//  BA    : [2][6400][256]     =  3,276,800   (b, pos, head*32+d)
//  AttOut: [16][1600][25][32] = 20,480,000   (bh, hw, p, d)   d-innermost!
#define OFF_PTOP 0
#define OFF_PBOT 2457600
#define OFF_TR   12288000
#define OFF_BA   13107200
#define OFF_ATT  16384000
#define WS_NEED_DENSE  (36864000ULL * 4ULL)   // 147.5 MB
// fallback (atomic) path needs only 65.5 MB

// ---------------------------------------------------------------------------
// Projection GEMM: P[kqv][bh][pos][32] = W[kqv] (256x256) @ X[b] (256 x npos)
// ---------------------------------------------------------------------------
__global__ __launch_bounds__(256) void proj_gemm(
    const float* __restrict__ X,
    const float* __restrict__ Wk,
    const float* __restrict__ Wq,
    const float* __restrict__ Wv,
    float* __restrict__ P,
    int npos)
{
  __shared__ float As[16][64];   // [k][oc]
  __shared__ float Bs[16][64];   // [k][pos]
  const int tid  = threadIdx.x;
  const int b    = blockIdx.z;
  const int oc0  = blockIdx.y * 64;   // 0..704 (768 oc total = 3 kqv * 256)
  const int pos0 = blockIdx.x * 64;
  const int tx   = tid & 15;          // -> oc quad (store-coalescing along d)
  const int ty   = tid >> 4;          // -> pos quad
  const int kqv  = oc0 >> 8;
  const int ocr  = oc0 & 255;
  const float* Wsel = (kqv == 0) ? Wk : ((kqv == 1) ? Wq : Wv);
  const float* Xb   = X + (size_t)b * NCH * npos;

  const int la_r = tid >> 2;          // 0..63 oc-in-tile
  const int la_c = (tid & 3) * 4;     // k
  const int lb_r = tid >> 4;          // 0..15 k
  const int lb_c = (tid & 15) * 4;    // pos

  float acc[4][4];
#pragma unroll
  for (int i = 0; i < 4; ++i)
#pragma unroll
    for (int j = 0; j < 4; ++j) acc[i][j] = 0.f;

  for (int kt = 0; kt < 256; kt += 16) {
    float4 av = *(const float4*)&Wsel[(size_t)(ocr + la_r) * 256 + kt + la_c];
    float4 bv = *(const float4*)&Xb[(size_t)(kt + lb_r) * npos + pos0 + lb_c];
    __syncthreads();
    As[la_c + 0][la_r] = av.x;
    As[la_c + 1][la_r] = av.y;
    As[la_c + 2][la_r] = av.z;
    As[la_c + 3][la_r] = av.w;
    *(float4*)&Bs[lb_r][lb_c] = bv;
    __syncthreads();
#pragma unroll
    for (int kk = 0; kk < 16; ++kk) {
      float a[4], bb[4];
      *(float4*)a  = *(const float4*)&As[kk][tx * 4];
      *(float4*)bb = *(const float4*)&Bs[kk][ty * 4];
#pragma unroll
      for (int i = 0; i < 4; ++i)
#pragma unroll
        for (int j = 0; j < 4; ++j) acc[i][j] += a[i] * bb[j];
    }
  }

  const int ocl  = oc0 + tx * 4;
  const int hd   = ocl & 255;
  const int head = hd >> 5;
  const int d0   = hd & 31;
  const int bh   = b * NHD + head;
  float* Pb = P + (size_t)(kqv * BN + bh) * npos * 32;
#pragma unroll
  for (int j = 0; j < 4; ++j) {
    const int pos = pos0 + ty * 4 + j;
    *(float4*)&Pb[(size_t)pos * 32 + d0] =
        make_float4(acc[0][j], acc[1][j], acc[2][j], acc[3][j]);
  }
}

// ---------------------------------------------------------------------------
// Staging helper: build one 26x32 row-major matrix in a LDS slot.
//   row 0      = top proj (clean d = 0..31)
//   row 1+a, b = bot flat index a*32+b of the d-major vector F[d*25+p]
// LDS linear layout offset(row j, col x) = j*32+x  == 32 + d*25 + p for bot.
// Scrambled write (lane v == d, stride 25): banks (25v+p)%32, conflict-free.
// ---------------------------------------------------------------------------
__device__ __forceinline__ void stage_rows(
    float* dst,                        // 832-float slot
    const float* __restrict__ Ptopr,   // top row (32 floats)
    const float* __restrict__ Pbotp,   // bot plane base for this (kqv,bh)
    int ho, int wo, int v, float scl)
{
  dst[v] = Ptopr[v] * scl;
#pragma unroll
  for (int p = 0; p < 25; ++p) {
    const int ki = p / 5, kj = p % 5;
    const int hb = 2 * ho - 2 + ki;
    const int wb = 2 * wo - 2 + kj;
    float val = 0.f;
    if (hb >= 0 && hb < HBs && wb >= 0 && wb < WBs)
      val = Pbotp[(size_t)(hb * WBs + wb) * 32 + v] * scl;
    dst[32 + v * 25 + p] = val;
  }
}

// ---------------------------------------------------------------------------
// Attention (dense path). One half-wave per position n.
// M[x][v] = sum_j Q[j][x]*V[j][v] (scaled);  out[i][v] = sum_x K[i][x]*M[x][v].
// Phase B results go to the (dead) SV slot at linear f=(i-1)*32+v, then are
// read back transposed (lds[v*25+j], conflict-free) and stored d-innermost:
//   AttOut[n][p*32+d]   (p = j, d = v)  -> coalesced fold reads.
// ---------------------------------------------------------------------------
__global__ __launch_bounds__(256, 3) void attn_dense(
    const float* __restrict__ Ptop,
    const float* __restrict__ Pbot,
    float* __restrict__ TR,
    float* __restrict__ AttOut)
{
  __shared__ float SQ[8][832];   // Q (scaled), reused for K in phase B
  __shared__ float SV[8][832];   // V in phase A, out-scratch in phase B

  const int tid  = threadIdx.x;
  const int widx = tid >> 6;
  const int lane = tid & 63;
  const int nsub = lane >> 5;
  const int v    = lane & 31;
  const int slot = widx * 2 + nsub;
  const int n    = (blockIdx.x * 4 + widx) * 2 + nsub;
  const int b    = n / (NHD * HWT);
  const int head = (n / HWT) % NHD;
  const int hw   = n % HWT;
  const int ho   = hw / WW, wo = hw % WW;
  const int bh   = b * NHD + head;
  const float scale = 0.17677669529663687f;  // 1/sqrt(32)

  float* SQs = &SQ[slot][0];
  float* SVs = &SV[slot][0];

  stage_rows(SQs, Ptop + ((size_t)(1 * BN + bh) * HWT + hw) * 32,
             Pbot + (size_t)(1 * BN + bh) * HWB * 32, ho, wo, v, scale);
  stage_rows(SVs, Ptop + ((size_t)(2 * BN + bh) * HWT + hw) * 32,
             Pbot + (size_t)(2 * BN + bh) * HWB * 32, ho, wo, v, 1.f);

  // phase A: M column v in registers
  float m[32];
#pragma unroll
  for (int x = 0; x < 32; ++x) m[x] = 0.f;

#pragma unroll 2
  for (int j = 0; j < 26; ++j) {
    const float vv = SVs[j * 32 + v];
    const float* qr = &SQs[j * 32];
#pragma unroll
    for (int c = 0; c < 8; ++c) {
      float4 t = *(const float4*)&qr[c * 4];
      m[c * 4 + 0] += t.x * vv;
      m[c * 4 + 1] += t.y * vv;
      m[c * 4 + 2] += t.z * vv;
      m[c * 4 + 3] += t.w * vv;
    }
  }

  // restage K into the Q slot (same-half-wave private; DS ops in-order)
  stage_rows(SQs, Ptop + ((size_t)(0 * BN + bh) * HWT + hw) * 32,
             Pbot + (size_t)(0 * BN + bh) * HWB * 32, ho, wo, v, 1.f);

  // phase B: out rows; row 0 -> TR, rows 1..25 -> SV scratch (bank = v)
  float* TRn = TR + ((size_t)(b * HWT + hw)) * 256 + head * 32;
#pragma unroll 2
  for (int i = 0; i < 26; ++i) {
    const float* kr = &SQs[i * 32];
    float s0 = 0.f, s1 = 0.f, s2 = 0.f, s3 = 0.f;
#pragma unroll
    for (int c = 0; c < 8; ++c) {
      float4 t = *(const float4*)&kr[c * 4];
      s0 += t.x * m[c * 4 + 0];
      s1 += t.y * m[c * 4 + 1];
      s2 += t.z * m[c * 4 + 2];
      s3 += t.w * m[c * 4 + 3];
    }
    const float o = (s0 + s1) + (s2 + s3);
    if (i == 0) TRn[v] = o;
    else        SVs[(i - 1) * 32 + v] = o;
  }

  // transpose out of LDS: lds[v*25+j] holds (d=v, p=j); store d-innermost
  float* AOn = AttOut + (size_t)n * 800;
#pragma unroll 5
  for (int j = 0; j < 25; ++j)
    AOn[j * 32 + v] = SVs[v * 25 + j];
}

// ---------------------------------------------------------------------------
// Fold gather (coalesced): BA[b][hb*80+wb][head*32+d] = sum over <=9 windows
//   of AttOut[(b*8+head)][ho*40+wo][p*32+d],  ki=hb+2-2ho, kj=wb+2-2wo.
// One wave = one pixel (uniform branches); thread = (d-quad, head); float4.
// ---------------------------------------------------------------------------
__global__ __launch_bounds__(256) void fold_gather(
    const float* __restrict__ AttOut,
    float* __restrict__ BA)
{
  const int t    = blockIdx.x * 256 + threadIdx.x;
  const int dq   = (t & 7) * 4;
  const int head = (t >> 3) & 7;
  const int pw   = t >> 6;          // b*HWB + pix
  const int pix  = pw % HWB;
  const int b    = pw / HWB;
  const int hb   = pix / WBs, wb = pix % WBs;

  const float* A = AttOut + (size_t)(b * NHD + head) * HWT * 800;
  float4 s = make_float4(0.f, 0.f, 0.f, 0.f);
  for (int ki = (hb & 1); ki < 5; ki += 2) {
    const int ho = (hb + 2 - ki) >> 1;
    if (ho < 0 || ho >= HH) continue;
    for (int kj = (wb & 1); kj < 5; kj += 2) {
      const int wo = (wb + 2 - kj) >> 1;
      if (wo < 0 || wo >= WW) continue;
      const float4 a4 = *(const float4*)&A[(size_t)(ho * WW + wo) * 800 +
                                           (ki * 5 + kj) * 32 + dq];
      s.x += a4.x; s.y += a4.y; s.z += a4.z; s.w += a4.w;
    }
  }
  *(float4*)&BA[(size_t)pw * 256 + head * 32 + dq] = s;
}

// ---------------------------------------------------------------------------
// Fallback attention (atomic fold) — used only if ws_size is too small.
// ---------------------------------------------------------------------------
__global__ __launch_bounds__(256) void attn_atomic(
    const float* __restrict__ Ptop,
    const float* __restrict__ Pbot,
    float* __restrict__ TR,
    float* __restrict__ BA)
{
  __shared__ float SQ[8][832];
  __shared__ float SV[8][832];

  const int tid  = threadIdx.x;
  const int widx = tid >> 6;
  const int lane = tid & 63;
  const int nsub = lane >> 5;
  const int v    = lane & 31;
  const int slot = widx * 2 + nsub;
  const int n    = (blockIdx.x * 4 + widx) * 2 + nsub;
  const int b    = n / (NHD * HWT);
  const int head = (n / HWT) % NHD;
  const int hw   = n % HWT;
  const int ho   = hw / WW, wo = hw % WW;
  const int bh   = b * NHD + head;
  const float scale = 0.17677669529663687f;

  float* SQs = &SQ[slot][0];
  float* SVs = &SV[slot][0];

  stage_rows(SQs, Ptop + ((size_t)(1 * BN + bh) * HWT + hw) * 32,
             Pbot + (size_t)(1 * BN + bh) * HWB * 32, ho, wo, v, scale);
  stage_rows(SVs, Ptop + ((size_t)(2 * BN + bh) * HWT + hw) * 32,
             Pbot + (size_t)(2 * BN + bh) * HWB * 32, ho, wo, v, 1.f);

  float m[32];
#pragma unroll
  for (int x = 0; x < 32; ++x) m[x] = 0.f;

#pragma unroll 2
  for (int j = 0; j < 26; ++j) {
    const float vv = SVs[j * 32 + v];
    const float* qr = &SQs[j * 32];
#pragma unroll
    for (int c = 0; c < 8; ++c) {
      float4 t = *(const float4*)&qr[c * 4];
      m[c * 4 + 0] += t.x * vv;
      m[c * 4 + 1] += t.y * vv;
      m[c * 4 + 2] += t.z * vv;
      m[c * 4 + 3] += t.w * vv;
    }
  }

  stage_rows(SQs, Ptop + ((size_t)(0 * BN + bh) * HWT + hw) * 32,
             Pbot + (size_t)(0 * BN + bh) * HWB * 32, ho, wo, v, 1.f);

  for (int i = 0; i < 26; ++i) {
    const float* kr = &SQs[i * 32];
    float s0 = 0.f, s1 = 0.f, s2 = 0.f, s3 = 0.f;
#pragma unroll
    for (int c = 0; c < 8; ++c) {
      float4 t = *(const float4*)&kr[c * 4];
      s0 += t.x * m[c * 4 + 0];
      s1 += t.y * m[c * 4 + 1];
      s2 += t.z * m[c * 4 + 2];
      s3 += t.w * m[c * 4 + 3];
    }
    const float o = (s0 + s1) + (s2 + s3);
    if (i == 0) {
      TR[((size_t)(b * HWT + hw)) * 256 + head * 32 + v] = o;
    } else {
      const int flat = (i - 1) * 32 + v;
      const int dd = flat / 25;
      const int p  = flat % 25;
      const int ki = p / 5, kj = p % 5;
      const int hb = 2 * ho - 2 + ki;
      const int wb = 2 * wo - 2 + kj;
      if (hb >= 0 && hb < HBs && wb >= 0 && wb < WBs)
        atomicAdd(&BA[((size_t)(b * HWB + hb * WBs + wb)) * 256 + head * 32 + dd], o);
    }
  }
}

// ---------------------------------------------------------------------------
// Fuse GEMM: Out[b][co][pos] = Wf (256x256) @ Xp[b][pos][256]^T
// ---------------------------------------------------------------------------
__global__ __launch_bounds__(256) void fuse_gemm(
    const float* __restrict__ Xp,   // [B][npos][256]
    const float* __restrict__ Wf,   // [256][256]
    float* __restrict__ Out,        // [B][256][npos]
    int npos)
{
  __shared__ float As[16][64];
  __shared__ float Bs[16][64];
  const int tid  = threadIdx.x;
  const int b    = blockIdx.z;
  const int co0  = blockIdx.y * 64;
  const int pos0 = blockIdx.x * 64;
  const int tx   = tid & 15;
  const int ty   = tid >> 4;
  const float* Xb = Xp + (size_t)b * npos * 256;

  const int la_r = tid >> 2;
  const int la_c = (tid & 3) * 4;

  float acc[4][4];
#pragma unroll
  for (int i = 0; i < 4; ++i)
#pragma unroll
    for (int j = 0; j < 4; ++j) acc[i][j] = 0.f;

  for (int kt = 0; kt < 256; kt += 16) {
    float4 av = *(const float4*)&Wf[(size_t)(co0 + la_r) * 256 + kt + la_c];
    float4 bv = *(const float4*)&Xb[(size_t)(pos0 + la_r) * 256 + kt + la_c];
    __syncthreads();
    As[la_c + 0][la_r] = av.x;
    As[la_c + 1][la_r] = av.y;
    As[la_c + 2][la_r] = av.z;
    As[la_c + 3][la_r] = av.w;
    Bs[la_c + 0][la_r] = bv.x;
    Bs[la_c + 1][la_r] = bv.y;
    Bs[la_c + 2][la_r] = bv.z;
    Bs[la_c + 3][la_r] = bv.w;
    __syncthreads();
#pragma unroll
    for (int kk = 0; kk < 16; ++kk) {
      float a[4], bb[4];
      *(float4*)a  = *(const float4*)&As[kk][ty * 4];
      *(float4*)bb = *(const float4*)&Bs[kk][tx * 4];
#pragma unroll
      for (int i = 0; i < 4; ++i)
#pragma unroll
        for (int j = 0; j < 4; ++j) acc[i][j] += a[i] * bb[j];
    }
  }

  float* Ob = Out + (size_t)b * NCH * npos;
#pragma unroll
  for (int i = 0; i < 4; ++i) {
    const int co = co0 + ty * 4 + i;
    *(float4*)&Ob[(size_t)co * npos + pos0 + tx * 4] =
        make_float4(acc[i][0], acc[i][1], acc[i][2], acc[i][3]);
  }
}

// ---------------------------------------------------------------------------
extern "C" void kernel_launch(void* const* d_in, const int* in_sizes, int n_in,
                              void* d_out, int out_size, void* d_ws, size_t ws_size,
                              hipStream_t stream) {
  (void)in_sizes; (void)n_in; (void)out_size;
  const float* top = (const float*)d_in[0];
  const float* bot = (const float*)d_in[1];
  const float* wtk = (const float*)d_in[2];
  const float* wtq = (const float*)d_in[3];
  const float* wtv = (const float*)d_in[4];
  const float* wbk = (const float*)d_in[5];
  const float* wbq = (const float*)d_in[6];
  const float* wbv = (const float*)d_in[7];
  const float* wtf = (const float*)d_in[8];
  const float* wbf = (const float*)d_in[9];

  float* ws   = (float*)d_ws;
  float* Ptop = ws + OFF_PTOP;
  float* Pbot = ws + OFF_PBOT;
  float* TR   = ws + OFF_TR;
  float* BA   = ws + OFF_BA;
  float* Att  = ws + OFF_ATT;

  proj_gemm<<<dim3(HWT / 64, 12, NB), 256, 0, stream>>>(top, wtk, wtq, wtv, Ptop, HWT);
  proj_gemm<<<dim3(HWB / 64, 12, NB), 256, 0, stream>>>(bot, wbk, wbq, wbv, Pbot, HWB);

  if (ws_size >= WS_NEED_DENSE) {
    // dense path: no atomics; fold via coalesced gather (BA fully overwritten)
    attn_dense<<<dim3(25600 / 8), 256, 0, stream>>>(Ptop, Pbot, TR, Att);
    fold_gather<<<dim3((NB * NHD * HWB * 8) / 256), 256, 0, stream>>>(Att, BA);
  } else {
    hipMemsetAsync(BA, 0, (size_t)NB * HWB * 256 * sizeof(float), stream);
    attn_atomic<<<dim3(25600 / 8), 256, 0, stream>>>(Ptop, Pbot, TR, BA);
  }

  fuse_gemm<<<dim3(HWT / 64, 4, NB), 256, 0, stream>>>(TR, wtf, (float*)d_out, HWT);
  fuse_gemm<<<dim3(HWB / 64, 4, NB), 256, 0, stream>>>(BA, wbf, (float*)d_out + (size_t)NB * NCH * HWT, HWB);
}